// Round 2
// baseline (590.845 us; speedup 1.0000x reference)
//
#include <hip/hip_runtime.h>
#include <math.h>

// Problem constants
#define T_TOK 1024
#define DIM 512
#define INTER 256
#define SINTER 1024
#define NEXP 64
#define TOPK 6

typedef unsigned short u16;
typedef unsigned int u32;

__device__ __forceinline__ float bflo(u32 u) { return __uint_as_float(u << 16); }
__device__ __forceinline__ float bfhi(u32 u) { return __uint_as_float(u & 0xffff0000u); }

__device__ __forceinline__ u16 f2bf(float f) {
    u32 u = __float_as_uint(f);
    return (u16)((u + 0x7fffu + ((u >> 16) & 1u)) >> 16);  // RNE
}

// load 8 consecutive elements (idx must be a multiple of 8) as floats
template<bool BF>
__device__ __forceinline__ void ld8(const void* p, size_t idx, float* f) {
    if (BF) {
        uint4 u = *(const uint4*)((const u16*)p + idx);
        f[0] = bflo(u.x); f[1] = bfhi(u.x);
        f[2] = bflo(u.y); f[3] = bfhi(u.y);
        f[4] = bflo(u.z); f[5] = bfhi(u.z);
        f[6] = bflo(u.w); f[7] = bfhi(u.w);
    } else {
        const float4* q = (const float4*)((const float*)p + idx);
        float4 a = q[0], b = q[1];
        f[0] = a.x; f[1] = a.y; f[2] = a.z; f[3] = a.w;
        f[4] = b.x; f[5] = b.y; f[6] = b.z; f[7] = b.w;
    }
}

// load 2 consecutive elements (idx even)
template<bool BF>
__device__ __forceinline__ void ld2(const void* p, size_t idx, float& a, float& b) {
    if (BF) { u32 w = *(const u32*)((const u16*)p + idx); a = bflo(w); b = bfhi(w); }
    else    { float2 v = *(const float2*)((const float*)p + idx); a = v.x; b = v.y; }
}

__device__ __forceinline__ void fma44(float& acc, const float* f, const float4& a, const float4& b) {
    acc = fmaf(f[0], a.x, acc); acc = fmaf(f[1], a.y, acc);
    acc = fmaf(f[2], a.z, acc); acc = fmaf(f[3], a.w, acc);
    acc = fmaf(f[4], b.x, acc); acc = fmaf(f[5], b.y, acc);
    acc = fmaf(f[6], b.z, acc); acc = fmaf(f[7], b.w, acc);
}

// ---------------- kernel P: dtype probe ----------------
// If x is bf16-packed, the low 16 bits of each 32-bit word are a genuine
// N(0,1) bf16 (exponent in [110,140] essentially always). If x is fp32,
// the low 16 bits are random mantissa bits (~12% hit rate). 512 samples.
__global__ void k_probe(const u32* __restrict__ xw, int* __restrict__ flag) {
    int cnt = 0;
    #pragma unroll
    for (int i = 0; i < 8; ++i) {
        u32 u = xw[threadIdx.x * 8 + i];
        u32 e = (u >> 7) & 0xffu;           // exponent of low-half-as-bf16
        cnt += (e >= 110 && e <= 140) ? 1 : 0;
    }
    #pragma unroll
    for (int off = 32; off; off >>= 1) cnt += __shfl_xor(cnt, off);
    if (threadIdx.x == 0) flag[0] = (cnt > 256) ? 1 : 0;
}

// ---------------- kernel 0: zero the expert counters ----------------
__global__ void k_init(int* counts) {
    counts[threadIdx.x] = 0;
}

// ---------------- kernel 1: router ----------------
template<bool BF>
__device__ __forceinline__ void router_body(const void* __restrict__ xg,
                                            const void* __restrict__ wg,
                                            int* __restrict__ counts,
                                            int* __restrict__ topki,
                                            float* __restrict__ topkw,
                                            float* xs, float* svals, int* sidx) {
    const int t = blockIdx.x;
    const int lane = threadIdx.x;

    ld8<BF>(xg, (size_t)t * DIM + lane * 8, &xs[lane * 8]);
    __syncthreads();

    // score for expert `lane`
    float acc = 0.f;
    for (int k = 0; k < 64; ++k) {
        float f[8]; ld8<BF>(wg, (size_t)lane * DIM + k * 8, f);
        float4 xa = *(const float4*)&xs[k * 8];
        float4 xb = *(const float4*)&xs[k * 8 + 4];
        fma44(acc, f, xa, xb);
    }

    float my = acc;
    for (int s = 0; s < TOPK; ++s) {
        float v = my; int id = lane;
        #pragma unroll
        for (int off = 32; off; off >>= 1) {
            float ov = __shfl_xor(v, off);
            int   oi = __shfl_xor(id, off);
            if (ov > v || (ov == v && oi < id)) { v = ov; id = oi; }
        }
        if (lane == 0) { svals[s] = v; sidx[s] = id; }
        if (lane == id) my = -INFINITY;
    }
    __syncthreads();
    if (lane == 0) {
        float m = svals[0], sum = 0.f, w[TOPK];
        #pragma unroll
        for (int s = 0; s < TOPK; ++s) { w[s] = __expf(svals[s] - m); sum += w[s]; }
        float inv = 1.f / sum;
        #pragma unroll
        for (int s = 0; s < TOPK; ++s) {
            int e = sidx[s];
            topki[t * TOPK + s] = e;
            topkw[t * TOPK + s] = w[s] * inv;
            atomicAdd(&counts[e], 1);
        }
    }
}

__global__ __launch_bounds__(64) void k_router(const void* xg, const void* wg,
                                               const int* __restrict__ flag,
                                               int* counts, int* topki, float* topkw) {
    __shared__ __align__(16) float xs[DIM];
    __shared__ float svals[TOPK];
    __shared__ int sidx[TOPK];
    if (*flag) router_body<true >(xg, wg, counts, topki, topkw, xs, svals, sidx);
    else       router_body<false>(xg, wg, counts, topki, topkw, xs, svals, sidx);
}

// ---------------- kernel 2: prefix sum over 64 experts ----------------
__global__ void k_prefix(const int* __restrict__ counts, int* __restrict__ offsets,
                         int* __restrict__ cursors) {
    if (threadIdx.x == 0) {
        int acc = 0;
        for (int e = 0; e < NEXP; ++e) { offsets[e] = acc; cursors[e] = acc; acc += counts[e]; }
    }
}

// ---------------- kernel 3: scatter tokens into expert buckets ----------------
__global__ void k_scatter(const int* __restrict__ topki, const float* __restrict__ topkw,
                          int* __restrict__ cursors, int* __restrict__ tokl,
                          float* __restrict__ wgtl) {
    int t = blockIdx.x * 256 + threadIdx.x;
    #pragma unroll
    for (int s = 0; s < TOPK; ++s) {
        int e = topki[t * TOPK + s];
        float w = topkw[t * TOPK + s];
        int pos = atomicAdd(&cursors[e], 1);
        tokl[pos] = t;
        wgtl[pos] = w;
    }
}

// ---------------- kernel 4: shared expert ----------------
template<bool BF>
__device__ __forceinline__ void shared_body(const void* __restrict__ xg,
                                            const void* __restrict__ wsg,
                                            const void* __restrict__ wsu,
                                            const void* __restrict__ wsd,
                                            float* __restrict__ accum,
                                            float* xs /*8*DIM*/, float* vs /*8*SINTER*/) {
    const int t0 = blockIdx.x * 8;
    const int tid = threadIdx.x;

    for (int idx = tid; idx < 8 * 64; idx += 256) {
        int r = idx >> 6, c = idx & 63;
        ld8<BF>(xg, (size_t)(t0 + r) * DIM + c * 8, &xs[r * DIM + c * 8]);
    }
    __syncthreads();

    for (int jc = 0; jc < 4; ++jc) {
        int j = jc * 256 + tid;
        float ag[8] = {0}, au[8] = {0};
        for (int k = 0; k < 64; ++k) {
            float fg[8], fu[8];
            ld8<BF>(wsg, (size_t)j * DIM + k * 8, fg);
            ld8<BF>(wsu, (size_t)j * DIM + k * 8, fu);
            #pragma unroll
            for (int r = 0; r < 8; ++r) {
                float4 xa = *(const float4*)&xs[r * DIM + k * 8];
                float4 xb = *(const float4*)&xs[r * DIM + k * 8 + 4];
                fma44(ag[r], fg, xa, xb);
                fma44(au[r], fu, xa, xb);
            }
        }
        #pragma unroll
        for (int r = 0; r < 8; ++r) {
            float g = ag[r];
            vs[r * SINTER + j] = g / (1.f + __expf(-g)) * au[r];
        }
    }
    __syncthreads();

    const int d0 = tid, d1 = tid + 256;
    float aca[8] = {0}, acb[8] = {0};
    for (int k = 0; k < 128; ++k) {
        float fa[8], fb[8];
        ld8<BF>(wsd, (size_t)d0 * SINTER + k * 8, fa);
        ld8<BF>(wsd, (size_t)d1 * SINTER + k * 8, fb);
        #pragma unroll
        for (int r = 0; r < 8; ++r) {
            float4 v0 = *(const float4*)&vs[r * SINTER + k * 8];
            float4 v1 = *(const float4*)&vs[r * SINTER + k * 8 + 4];
            fma44(aca[r], fa, v0, v1);
            fma44(acb[r], fb, v0, v1);
        }
    }
    #pragma unroll
    for (int r = 0; r < 8; ++r) {
        accum[(size_t)(t0 + r) * DIM + d0] = aca[r];
        accum[(size_t)(t0 + r) * DIM + d1] = acb[r];
    }
}

__global__ __launch_bounds__(256) void k_shared(const void* xg, const void* wsg,
                                                const void* wsu, const void* wsd,
                                                const int* __restrict__ flag,
                                                float* accum) {
    __shared__ __align__(16) float xs[8 * DIM];      // 16 KB
    __shared__ __align__(16) float vs[8 * SINTER];   // 32 KB
    if (*flag) shared_body<true >(xg, wsg, wsu, wsd, accum, xs, vs);
    else       shared_body<false>(xg, wsg, wsu, wsd, accum, xs, vs);
}

// ---------------- kernel 5: routed experts ----------------
template<bool BF>
__device__ __forceinline__ void routed_body(const void* __restrict__ xg,
                                            const void* __restrict__ w1,
                                            const void* __restrict__ w2,
                                            const void* __restrict__ w3,
                                            const int* __restrict__ offsets,
                                            const int* __restrict__ counts,
                                            const int* __restrict__ tokl,
                                            const float* __restrict__ wgtl,
                                            float* __restrict__ accum,
                                            float* xs /*16*DIM*/, float* hs /*16*INTER*/,
                                            int* stok, float* ssw) {
    const int e = blockIdx.x & 63;
    const int slice = blockIdx.x >> 6;   // 0..3
    const int tid = threadIdx.x;
    const int n = counts[e];
    const int base = offsets[e];
    const size_t wbase = (size_t)e * INTER * DIM;

    for (int tile = slice * 16; tile < n; tile += 64) {
        const int nt = min(16, n - tile);
        __syncthreads();  // protect stok/hs from previous iteration
        if (tid < 16) {
            int ok = tid < nt;
            stok[tid] = ok ? tokl[base + tile + tid] : 0;
            ssw[tid]  = ok ? wgtl[base + tile + tid] : 0.f;
        }
        __syncthreads();
        for (int idx = tid; idx < 16 * 64; idx += 256) {
            int r = idx >> 6, c = idx & 63;
            float* xp = &xs[r * DIM + c * 8];
            if (r < nt) {
                ld8<BF>(xg, (size_t)stok[r] * DIM + c * 8, xp);
            } else {
                #pragma unroll
                for (int q = 0; q < 8; ++q) xp[q] = 0.f;
            }
        }
        __syncthreads();

        // H = silu(X W1^T) * (X W3^T) * token_weight ; thread owns i = tid
        {
            float a1[16] = {0}, a3[16] = {0};
            for (int k = 0; k < 64; ++k) {
                float f1[8], f3[8];
                ld8<BF>(w1, wbase + (size_t)tid * DIM + k * 8, f1);
                ld8<BF>(w3, wbase + (size_t)tid * DIM + k * 8, f3);
                #pragma unroll
                for (int t = 0; t < 16; ++t) {
                    float4 xa = *(const float4*)&xs[t * DIM + k * 8];
                    float4 xb = *(const float4*)&xs[t * DIM + k * 8 + 4];
                    fma44(a1[t], f1, xa, xb);
                    fma44(a3[t], f3, xa, xb);
                }
            }
            #pragma unroll
            for (int t = 0; t < 16; ++t) {
                float g = a1[t];
                hs[t * INTER + tid] = g / (1.f + __expf(-g)) * a3[t] * ssw[t];
            }
        }
        __syncthreads();

        // Y = H @ W2 ; thread owns d0 = 2*tid, d0+1
        {
            const int d0 = 2 * tid;
            float ay0[16] = {0}, ay1[16] = {0};
            for (int i = 0; i < INTER; i += 4) {
                float b0[4], b1[4];
                #pragma unroll
                for (int ii = 0; ii < 4; ++ii)
                    ld2<BF>(w2, wbase + (size_t)(i + ii) * DIM + d0, b0[ii], b1[ii]);
                #pragma unroll
                for (int t = 0; t < 16; ++t) {
                    float4 h4 = *(const float4*)&hs[t * INTER + i];
                    ay0[t] = fmaf(h4.x, b0[0], ay0[t]); ay0[t] = fmaf(h4.y, b0[1], ay0[t]);
                    ay0[t] = fmaf(h4.z, b0[2], ay0[t]); ay0[t] = fmaf(h4.w, b0[3], ay0[t]);
                    ay1[t] = fmaf(h4.x, b1[0], ay1[t]); ay1[t] = fmaf(h4.y, b1[1], ay1[t]);
                    ay1[t] = fmaf(h4.z, b1[2], ay1[t]); ay1[t] = fmaf(h4.w, b1[3], ay1[t]);
                }
            }
            for (int t = 0; t < nt; ++t) {
                float* dst = &accum[(size_t)stok[t] * DIM + d0];
                atomicAdd(dst, ay0[t]);
                atomicAdd(dst + 1, ay1[t]);
            }
        }
    }
}

__global__ __launch_bounds__(256) void k_routed(const void* xg, const void* w1,
                                                const void* w2, const void* w3,
                                                const int* __restrict__ flag,
                                                const int* offsets, const int* counts,
                                                const int* tokl, const float* wgtl,
                                                float* accum) {
    __shared__ __align__(16) float xs[16 * DIM];    // 32 KB
    __shared__ __align__(16) float hs[16 * INTER];  // 16 KB
    __shared__ int   stok[16];
    __shared__ float ssw[16];
    if (*flag) routed_body<true >(xg, w1, w2, w3, offsets, counts, tokl, wgtl, accum, xs, hs, stok, ssw);
    else       routed_body<false>(xg, w1, w2, w3, offsets, counts, tokl, wgtl, accum, xs, hs, stok, ssw);
}

// ---------------- kernel 6: fp32 accum -> output (dtype per flag) ----------------
__global__ void k_final(const float* __restrict__ accum, void* __restrict__ out,
                        const int* __restrict__ flag) {
    int i = blockIdx.x * 256 + threadIdx.x;
    float2 v = ((const float2*)accum)[i];
    if (*flag) {
        ((u32*)out)[i] = (u32)f2bf(v.x) | ((u32)f2bf(v.y) << 16);
    } else {
        ((float2*)out)[i] = v;
    }
}

extern "C" void kernel_launch(void* const* d_in, const int* in_sizes, int n_in,
                              void* d_out, int out_size, void* d_ws, size_t ws_size,
                              hipStream_t stream) {
    const void* x   = d_in[0];
    const void* wg  = d_in[1];
    const void* w1  = d_in[2];
    const void* w2  = d_in[3];
    const void* w3  = d_in[4];
    const void* wsg = d_in[5];
    const void* wsu = d_in[6];
    const void* wsd = d_in[7];

    char* ws = (char*)d_ws;
    float* accum  = (float*)ws;                              // 1024*512*4 = 2 MB
    int* counts   = (int*)(ws + (size_t)T_TOK * DIM * 4);
    int* offsets  = counts + 64;
    int* cursors  = offsets + 64;
    int* topki    = cursors + 64;                            // 6144 ints
    float* topkw  = (float*)(topki + T_TOK * TOPK);          // 6144 floats
    int* tokl     = (int*)(topkw + T_TOK * TOPK);            // 6144 ints
    float* wgtl   = (float*)(tokl + T_TOK * TOPK);           // 6144 floats
    int* flag     = (int*)(wgtl + T_TOK * TOPK);

    k_probe  <<<1, 64, 0, stream>>>((const u32*)x, flag);
    k_init   <<<1, 64, 0, stream>>>(counts);
    k_router <<<T_TOK, 64, 0, stream>>>(x, wg, flag, counts, topki, topkw);
    k_prefix <<<1, 64, 0, stream>>>(counts, offsets, cursors);
    k_scatter<<<4, 256, 0, stream>>>(topki, topkw, cursors, tokl, wgtl);
    k_shared <<<128, 256, 0, stream>>>(x, wsg, wsu, wsd, flag, accum);
    k_routed <<<256, 256, 0, stream>>>(x, w1, w2, w3, flag, offsets, counts, tokl, wgtl, accum);
    k_final  <<<1024, 256, 0, stream>>>(accum, d_out, flag);
}